// Round 6
// baseline (364.947 us; speedup 1.0000x reference)
//
#include <hip/hip_runtime.h>
#include <hip/hip_bf16.h>
#include <cstdint>

#define NB 4
#define NS 2048
#define ND 1024
#define NH 16
#define NDH 64
#define NM (NB*NS)       // 8192
#define N3D (3*ND)       // 3072

typedef __attribute__((ext_vector_type(8))) short short8;
typedef __attribute__((ext_vector_type(4))) float f32x4;
typedef __attribute__((ext_vector_type(4))) unsigned short us4;

__device__ __forceinline__ float bf2f(unsigned short u) {
  unsigned int i = ((unsigned int)u) << 16;
  return __builtin_bit_cast(float, i);
}
__device__ __forceinline__ unsigned short f2bf(float f) {
  unsigned int i = __builtin_bit_cast(unsigned int, f);
  i = (i + 0x7FFFu + ((i >> 16) & 1u)) >> 16;
  return (unsigned short)i;
}

#define GLD16(g, l) __builtin_amdgcn_global_load_lds( \
    (__attribute__((address_space(1))) void*)(void*)(g), \
    (__attribute__((address_space(3))) void*)(l), 16, 0, 0)

// ------------------------------------------------------------ f32 -> bf16 cast
__global__ __launch_bounds__(256) void cvt_bf16_k(
    const float* __restrict__ in, unsigned short* __restrict__ out, int n)
{
  const int i = (blockIdx.x * 256 + threadIdx.x) * 4;
  if (i + 3 < n) {
    const f32x4 v = *(const f32x4*)(in + i);
    us4 o = {f2bf(v[0]), f2bf(v[1]), f2bf(v[2]), f2bf(v[3])};
    *(us4*)(out + i) = o;
  }
}

// --------------------------------------------- f32 [rows][cols] -> bf16 [cols][rows]
__global__ __launch_bounds__(256) void transpose_cvt_k(
    const float* __restrict__ in, unsigned short* __restrict__ out,
    int rows, int cols)
{
  __shared__ unsigned short tile[32][33];
  const int c0 = blockIdx.x * 32, r0 = blockIdx.y * 32;
  const int tx = threadIdx.x & 31, ty = threadIdx.x >> 5;   // ty 0..7
  #pragma unroll
  for (int i = ty; i < 32; i += 8)
    tile[i][tx] = f2bf(in[(size_t)(r0 + i) * cols + (c0 + tx)]);
  __syncthreads();
  #pragma unroll
  for (int i = ty; i < 32; i += 8)
    out[(size_t)(c0 + i) * rows + (r0 + tx)] = tile[tx][i];
}

// ---------------------------------- V columns of qkv -> Vt[bh][d=64][s=2048]
__global__ __launch_bounds__(256) void vt_transpose_k(
    const unsigned short* __restrict__ qkv, unsigned short* __restrict__ vt)
{
  __shared__ unsigned short tile[32][33];
  const int dt = blockIdx.x & 1;           // 2 d-tiles
  const int st = (blockIdx.x >> 1) & 63;   // 64 s-tiles
  const int bh = blockIdx.x >> 7;          // 64 (b,h)
  const int b = bh >> 4, h = bh & 15;
  const int tx = threadIdx.x & 31, ty = threadIdx.x >> 5;
  const int s0 = st * 32, d0 = dt * 32;
  const unsigned short* src = qkv + (size_t)b * NS * N3D + 2 * ND + h * NDH;
  #pragma unroll
  for (int i = ty; i < 32; i += 8)
    tile[i][tx] = src[(size_t)(s0 + i) * N3D + d0 + tx];
  __syncthreads();
  unsigned short* dst = vt + (size_t)bh * NDH * NS;
  #pragma unroll
  for (int i = ty; i < 32; i += 8)
    dst[(size_t)(d0 + i) * NS + s0 + tx] = tile[tx][i];
}

// ------------------------------------------------- GEMM  C = A * Bt^T + bias
// A[M][K] bf16 row-major, Bt[N][K] bf16 row-major, f32 bias. 128x128 tile,
// BK=32, 4 waves (2x2 of 64x64), global_load_lds staging (m97 structure).
// XCD-aware bijective blockIdx swizzle (T1; nwg % 8 == 0 for all our shapes).
template<bool OUT_F32>
__global__ __launch_bounds__(256) void gemm_bt_bias(
    const unsigned short* __restrict__ A,
    const unsigned short* __restrict__ Bt,
    const float* __restrict__ bias,
    unsigned short* __restrict__ Cb,
    float* __restrict__ Cf,
    int M, int N, int K)
{
  __shared__ __align__(16) unsigned short Alds[128 * 32];
  __shared__ __align__(16) unsigned short Blds[128 * 32];
  const int nbn = N >> 7;
  const int nwg = (M >> 7) * nbn;
  const int cpx = nwg >> 3;
  const int tid = (blockIdx.x & 7) * cpx + (blockIdx.x >> 3);
  const int bm = tid / nbn, bn = tid % nbn;
  const int m0 = bm << 7, n0 = bn << 7;
  const int w = threadIdx.x >> 6, l = threadIdx.x & 63;
  const int wr = w >> 1, wc = w & 1;
  const int lr = l & 15, lg = l >> 4;

  const unsigned short* gA = A + (size_t)(m0 + w * 32 + (l >> 2)) * K + (l & 3) * 8;
  const unsigned short* gB = Bt + (size_t)(n0 + w * 32 + (l >> 2)) * K + (l & 3) * 8;
  unsigned short* lA = Alds + (w * 32) * 32;   // wave-uniform LDS base
  unsigned short* lB = Blds + (w * 32) * 32;

  f32x4 acc[4][4] = {};

  for (int k0 = 0; k0 < K; k0 += 32) {
    GLD16(gA + k0, lA);
    GLD16(gA + k0 + (size_t)16 * K, lA + 16 * 32);
    GLD16(gB + k0, lB);
    GLD16(gB + k0 + (size_t)16 * K, lB + 16 * 32);
    __syncthreads();

    short8 a[4], b[4];
    #pragma unroll
    for (int i = 0; i < 4; ++i)
      a[i] = *(const short8*)(Alds + (wr * 64 + i * 16 + lr) * 32 + lg * 8);
    #pragma unroll
    for (int j = 0; j < 4; ++j)
      b[j] = *(const short8*)(Blds + (wc * 64 + j * 16 + lr) * 32 + lg * 8);

    #pragma unroll
    for (int i = 0; i < 4; ++i)
      #pragma unroll
      for (int j = 0; j < 4; ++j)
        acc[i][j] = __builtin_amdgcn_mfma_f32_16x16x32_bf16(a[i], b[j], acc[i][j], 0, 0, 0);
    __syncthreads();
  }

  #pragma unroll
  for (int j = 0; j < 4; ++j) {
    const int col = n0 + wc * 64 + j * 16 + lr;
    const float bv = bias[col];
    #pragma unroll
    for (int i = 0; i < 4; ++i) {
      #pragma unroll
      for (int r = 0; r < 4; ++r) {
        const int row = m0 + wr * 64 + i * 16 + lg * 4 + r;
        const float v = acc[i][j][r] + bv;
        if (OUT_F32) Cf[(size_t)row * N + col] = v;
        else         Cb[(size_t)row * N + col] = f2bf(v);
      }
    }
  }
}

// ----------------------------------------------------- causal flash attention
// Causal load balancing via complementary pairing: q split into 128 half-chunks
// of 16 rows; wave p handles chunk p THEN chunk 127-p (state reused) -> every
// wave ~33 iterations -> every block uniform -> occupancy holds at static
// 16 waves/CU with no decay tail. 4-wave blocks share bh + adjacent chunks so
// K/V loads hit L1 in near-lockstep. Block id = g*64+bh keeps bh%8 -> XCD
// stable (8 bh x 512KB K/V = 4MB = one XCD L2).
// Swapped QK^T (lane owns one q-row slice), KVBLK=64, defer-max THR=8,
// Q pre-scaled by 0.125 (exact bf16 exponent shift).
__global__ __launch_bounds__(256) void attn_fwd(
    const unsigned short* __restrict__ qkv,
    const unsigned short* __restrict__ Vt,
    unsigned short* __restrict__ out)
{
  __shared__ __align__(16) char Plds[4][16 * 128];   // per-wave [16 q][64 k] bf16, swizzled
  const int bid = blockIdx.x;
  const int bh = bid & 63;               // XCD = bh % 8, stable across g
  const int g  = bid >> 6;               // 0..15
  const int b = bh >> 4, h = bh & 15;
  const int w = threadIdx.x >> 6, l = threadIdx.x & 63;
  const int lr = l & 15, lg = l >> 4;
  const int pidx = g * 4 + w;            // 0..63

  const size_t rs = N3D;
  const unsigned short* Qb = qkv + (size_t)b * NS * rs + (size_t)h * NDH;
  const unsigned short* Kb = Qb + ND;
  const unsigned short* Vb = Vt + (size_t)bh * NDH * NS;

  char* pw = &Plds[w][0];
  const int swz = (lr & 7) << 4;

  #pragma unroll 1
  for (int pass = 0; pass < 2; ++pass) {
    const int q0 = (pass == 0 ? pidx : 127 - pidx) * 16;

    // Q fragment for rows q0+lr, pre-scaled by 1/8 (exact bf16 exponent shift)
    short8 qf0, qf1;
    {
      const unsigned short* qrow = Qb + (size_t)(q0 + lr) * rs + lg * 8;
      qf0 = *(const short8*)(qrow);
      qf1 = *(const short8*)(qrow + 32);
      #pragma unroll
      for (int j = 0; j < 8; ++j) {
        qf0[j] = (short)f2bf(bf2f((unsigned short)qf0[j]) * 0.125f);
        qf1[j] = (short)f2bf(bf2f((unsigned short)qf1[j]) * 0.125f);
      }
    }

    float m_run = -__builtin_inff(), l_run = 0.f;
    f32x4 o[4] = {};

    const int ktmax = (q0 + 15) >> 6;
    #pragma unroll 1
    for (int kt = 0; kt <= ktmax; ++kt) {
      const int kbase = kt << 6;

      // V fragments (B-operand of PV): lane holds V[kbase+kk*32+lg*8+j][nb*16+lr]
      short8 vf[4][2];
      #pragma unroll
      for (int nb = 0; nb < 4; ++nb)
        #pragma unroll
        for (int kk = 0; kk < 2; ++kk)
          vf[nb][kk] = *(const short8*)(Vb + (size_t)(nb * 16 + lr) * NS + kbase + kk * 32 + lg * 8);

      // K loads + swapped QK^T: s[ks] = S^T[key=kbase+ks*16+lg*4+r][q=q0+lr]
      f32x4 s[4] = {};
      #pragma unroll
      for (int ks = 0; ks < 4; ++ks) {
        const unsigned short* krow = Kb + (size_t)(kbase + ks * 16 + lr) * rs + lg * 8;
        short8 k0 = *(const short8*)(krow);
        short8 k1 = *(const short8*)(krow + 32);
        s[ks] = __builtin_amdgcn_mfma_f32_16x16x32_bf16(k0, qf0, s[ks], 0, 0, 0);
        s[ks] = __builtin_amdgcn_mfma_f32_16x16x32_bf16(k1, qf1, s[ks], 0, 0, 0);
      }

      const bool domask = (kbase + 63 > q0);   // wave-uniform
      const int qi = q0 + lr;
      float v[16];
      #pragma unroll
      for (int ks = 0; ks < 4; ++ks)
        #pragma unroll
        for (int r = 0; r < 4; ++r)
          v[ks * 4 + r] = s[ks][r];
      if (domask) {
        #pragma unroll
        for (int ks = 0; ks < 4; ++ks)
          #pragma unroll
          for (int r = 0; r < 4; ++r)
            if (kbase + ks * 16 + lg * 4 + r > qi) v[ks * 4 + r] = -__builtin_inff();
      }
      // row max: local tree + 2 shuffles over the lg axis
      float a0 = fmaxf(v[0], v[1]),  a1 = fmaxf(v[2], v[3]);
      float a2 = fmaxf(v[4], v[5]),  a3 = fmaxf(v[6], v[7]);
      float a4 = fmaxf(v[8], v[9]),  a5 = fmaxf(v[10], v[11]);
      float a6 = fmaxf(v[12], v[13]), a7 = fmaxf(v[14], v[15]);
      float b0 = fmaxf(a0, a1), b1 = fmaxf(a2, a3), b2 = fmaxf(a4, a5), b3 = fmaxf(a6, a7);
      float mx = fmaxf(fmaxf(b0, b1), fmaxf(b2, b3));
      mx = fmaxf(mx, __shfl_xor(mx, 16));
      mx = fmaxf(mx, __shfl_xor(mx, 32));

      const float mold = m_run;
      if (__any(mx > mold + 8.0f)) {           // T13 defer-max
        const float mnew = fmaxf(mold, mx);
        const float sf = __expf(mold - mnew);
        m_run = mnew;
        l_run *= sf;
        #pragma unroll
        for (int rr = 0; rr < 4; ++rr) {
          const float sfo = __shfl(sf, lg * 4 + rr);
          #pragma unroll
          for (int nb = 0; nb < 4; ++nb) o[nb][rr] *= sfo;
        }
      }
      const float mc = m_run;
      float p[16];
      #pragma unroll
      for (int i = 0; i < 16; ++i) p[i] = __expf(v[i] - mc);
      float s0 = (p[0] + p[1]) + (p[2] + p[3]);
      float s1 = (p[4] + p[5]) + (p[6] + p[7]);
      float s2 = (p[8] + p[9]) + (p[10] + p[11]);
      float s3 = (p[12] + p[13]) + (p[14] + p[15]);
      float rsum = (s0 + s1) + (s2 + s3);
      rsum += __shfl_xor(rsum, 16);
      rsum += __shfl_xor(rsum, 32);
      l_run += rsum;

      // P write: lane's 4 consecutive k at row q -> packed b64, swizzled
      #pragma unroll
      for (int ks = 0; ks < 4; ++ks) {
        us4 pk = {f2bf(p[ks * 4]), f2bf(p[ks * 4 + 1]), f2bf(p[ks * 4 + 2]), f2bf(p[ks * 4 + 3])};
        *(us4*)(pw + (((lr * 128) + ks * 32 + lg * 8) ^ swz)) = pk;
      }

      asm volatile("s_waitcnt lgkmcnt(0)" ::: "memory");   // same-wave write->read
      __builtin_amdgcn_sched_barrier(0);

      #pragma unroll
      for (int kk = 0; kk < 2; ++kk) {
        short8 pf = *(const short8*)(pw + (((lr * 128) + kk * 64 + lg * 16) ^ swz));
        #pragma unroll
        for (int nb = 0; nb < 4; ++nb)
          o[nb] = __builtin_amdgcn_mfma_f32_16x16x32_bf16(pf, vf[nb][kk], o[nb], 0, 0, 0);
      }
    }

    // epilogue: o rows are q=lg*4+rr; fetch row sum from owning lane
    #pragma unroll
    for (int rr = 0; rr < 4; ++rr) {
      const float lq = __shfl(l_run, lg * 4 + rr);
      const float inv = 1.0f / lq;
      const int qi = q0 + lg * 4 + rr;
      #pragma unroll
      for (int nb = 0; nb < 4; ++nb)
        out[(size_t)(b * NS + qi) * ND + h * NDH + nb * 16 + lr] = f2bf(o[nb][rr] * inv);
    }
  }
}

// --------------------------------------------------------------------- launch
extern "C" void kernel_launch(void* const* d_in, const int* in_sizes, int n_in,
                              void* d_out, int out_size, void* d_ws, size_t ws_size,
                              hipStream_t stream) {
  const float* x     = (const float*)d_in[0];
  const float* w_in  = (const float*)d_in[1];
  const float* b_in  = (const float*)d_in[2];
  const float* w_out = (const float*)d_in[3];
  const float* b_out = (const float*)d_in[4];
  float* out = (float*)d_out;

  char* ws = (char*)d_ws;
  size_t off = 0;
  unsigned short* x_bf    = (unsigned short*)(ws + off); off += (size_t)NM * ND * 2;    // 16 MiB
  unsigned short* qkv     = (unsigned short*)(ws + off); off += (size_t)NM * N3D * 2;   // 48 MiB
  unsigned short* attn    = (unsigned short*)(ws + off); off += (size_t)NM * ND * 2;    // 16 MiB
  unsigned short* w_in_t  = (unsigned short*)(ws + off); off += (size_t)N3D * ND * 2;   //  6 MiB
  unsigned short* w_out_t = (unsigned short*)(ws + off); off += (size_t)ND * ND * 2;    //  2 MiB
  // Vt aliases x_bf: x_bf is dead after GEMM1, vt_transpose runs after GEMM1.
  unsigned short* vt = x_bf;                                                            // 16 MiB

  // x -> bf16
  cvt_bf16_k<<<dim3((NM * ND) / (256 * 4)), 256, 0, stream>>>(x, x_bf, NM * ND);
  // weight transposes + cast: w[K][N] f32 -> wt[N][K] bf16
  transpose_cvt_k<<<dim3(N3D / 32, ND / 32), 256, 0, stream>>>(w_in, w_in_t, ND, N3D);
  transpose_cvt_k<<<dim3(ND / 32, ND / 32), 256, 0, stream>>>(w_out, w_out_t, ND, ND);

  // qkv = x @ w_in + b_in            (bf16 out)
  gemm_bt_bias<false><<<dim3((NM / 128) * (N3D / 128)), 256, 0, stream>>>(
      x_bf, w_in_t, b_in, qkv, nullptr, NM, N3D, ND);

  // V -> Vt (transposed per head)
  vt_transpose_k<<<dim3(64 * 64 * 2), 256, 0, stream>>>(qkv, vt);

  // attention: 1024 uniform blocks (complementary q-chunk pairing)
  attn_fwd<<<dim3(64 * 16), 256, 0, stream>>>(qkv, vt, attn);

  // out = attn @ w_out + b_out       (f32 out)
  gemm_bt_bias<true><<<dim3((NM / 128) * (ND / 128)), 256, 0, stream>>>(
      attn, w_out_t, b_out, nullptr, out, NM, ND, ND);
}

// Round 7
// 256.006 us; speedup vs baseline: 1.4255x; 1.4255x over previous
//
#include <hip/hip_runtime.h>
#include <hip/hip_bf16.h>
#include <cstdint>

#define NB 4
#define NS 2048
#define ND 1024
#define NH 16
#define NDH 64
#define NM (NB*NS)       // 8192
#define N3D (3*ND)       // 3072

typedef __attribute__((ext_vector_type(8))) short short8;
typedef __attribute__((ext_vector_type(4))) float f32x4;
typedef __attribute__((ext_vector_type(4))) unsigned short us4;

__device__ __forceinline__ float bf2f(unsigned short u) {
  unsigned int i = ((unsigned int)u) << 16;
  return __builtin_bit_cast(float, i);
}
__device__ __forceinline__ unsigned short f2bf(float f) {
  unsigned int i = __builtin_bit_cast(unsigned int, f);
  i = (i + 0x7FFFu + ((i >> 16) & 1u)) >> 16;
  return (unsigned short)i;
}

#define GLD16(g, l) __builtin_amdgcn_global_load_lds( \
    (__attribute__((address_space(1))) void*)(void*)(g), \
    (__attribute__((address_space(3))) void*)(l), 16, 0, 0)

// ------------------------------------------------------------ f32 -> bf16 cast
__global__ __launch_bounds__(256) void cvt_bf16_k(
    const float* __restrict__ in, unsigned short* __restrict__ out, int n)
{
  const int i = (blockIdx.x * 256 + threadIdx.x) * 4;
  if (i + 3 < n) {
    const f32x4 v = *(const f32x4*)(in + i);
    us4 o = {f2bf(v[0]), f2bf(v[1]), f2bf(v[2]), f2bf(v[3])};
    *(us4*)(out + i) = o;
  }
}

// --------------------------------------------- f32 [rows][cols] -> bf16 [cols][rows]
__global__ __launch_bounds__(256) void transpose_cvt_k(
    const float* __restrict__ in, unsigned short* __restrict__ out,
    int rows, int cols)
{
  __shared__ unsigned short tile[32][33];
  const int c0 = blockIdx.x * 32, r0 = blockIdx.y * 32;
  const int tx = threadIdx.x & 31, ty = threadIdx.x >> 5;   // ty 0..7
  #pragma unroll
  for (int i = ty; i < 32; i += 8)
    tile[i][tx] = f2bf(in[(size_t)(r0 + i) * cols + (c0 + tx)]);
  __syncthreads();
  #pragma unroll
  for (int i = ty; i < 32; i += 8)
    out[(size_t)(c0 + i) * rows + (r0 + tx)] = tile[tx][i];
}

// ---------------------------------- V columns of qkv -> Vt[bh][d=64][s=2048]
__global__ __launch_bounds__(256) void vt_transpose_k(
    const unsigned short* __restrict__ qkv, unsigned short* __restrict__ vt)
{
  __shared__ unsigned short tile[32][33];
  const int dt = blockIdx.x & 1;           // 2 d-tiles
  const int st = (blockIdx.x >> 1) & 63;   // 64 s-tiles
  const int bh = blockIdx.x >> 7;          // 64 (b,h)
  const int b = bh >> 4, h = bh & 15;
  const int tx = threadIdx.x & 31, ty = threadIdx.x >> 5;
  const int s0 = st * 32, d0 = dt * 32;
  const unsigned short* src = qkv + (size_t)b * NS * N3D + 2 * ND + h * NDH;
  #pragma unroll
  for (int i = ty; i < 32; i += 8)
    tile[i][tx] = src[(size_t)(s0 + i) * N3D + d0 + tx];
  __syncthreads();
  unsigned short* dst = vt + (size_t)bh * NDH * NS;
  #pragma unroll
  for (int i = ty; i < 32; i += 8)
    dst[(size_t)(d0 + i) * NS + s0 + tx] = tile[tx][i];
}

// ------------------------------------------------- GEMM  C = A * Bt^T + bias
// A[M][K] bf16 row-major, Bt[N][K] bf16 row-major, f32 bias. 128x128 tile,
// BK=32, 4 waves (2x2 of 64x64), global_load_lds staging (m97 structure).
// XCD-aware bijective blockIdx swizzle (T1; nwg % 8 == 0 for all our shapes).
template<bool OUT_F32>
__global__ __launch_bounds__(256) void gemm_bt_bias(
    const unsigned short* __restrict__ A,
    const unsigned short* __restrict__ Bt,
    const float* __restrict__ bias,
    unsigned short* __restrict__ Cb,
    float* __restrict__ Cf,
    int M, int N, int K)
{
  __shared__ __align__(16) unsigned short Alds[128 * 32];
  __shared__ __align__(16) unsigned short Blds[128 * 32];
  const int nbn = N >> 7;
  const int nwg = (M >> 7) * nbn;
  const int cpx = nwg >> 3;
  const int tid = (blockIdx.x & 7) * cpx + (blockIdx.x >> 3);
  const int bm = tid / nbn, bn = tid % nbn;
  const int m0 = bm << 7, n0 = bn << 7;
  const int w = threadIdx.x >> 6, l = threadIdx.x & 63;
  const int wr = w >> 1, wc = w & 1;
  const int lr = l & 15, lg = l >> 4;

  const unsigned short* gA = A + (size_t)(m0 + w * 32 + (l >> 2)) * K + (l & 3) * 8;
  const unsigned short* gB = Bt + (size_t)(n0 + w * 32 + (l >> 2)) * K + (l & 3) * 8;
  unsigned short* lA = Alds + (w * 32) * 32;   // wave-uniform LDS base
  unsigned short* lB = Blds + (w * 32) * 32;

  f32x4 acc[4][4] = {};

  for (int k0 = 0; k0 < K; k0 += 32) {
    GLD16(gA + k0, lA);
    GLD16(gA + k0 + (size_t)16 * K, lA + 16 * 32);
    GLD16(gB + k0, lB);
    GLD16(gB + k0 + (size_t)16 * K, lB + 16 * 32);
    __syncthreads();

    short8 a[4], b[4];
    #pragma unroll
    for (int i = 0; i < 4; ++i)
      a[i] = *(const short8*)(Alds + (wr * 64 + i * 16 + lr) * 32 + lg * 8);
    #pragma unroll
    for (int j = 0; j < 4; ++j)
      b[j] = *(const short8*)(Blds + (wc * 64 + j * 16 + lr) * 32 + lg * 8);

    #pragma unroll
    for (int i = 0; i < 4; ++i)
      #pragma unroll
      for (int j = 0; j < 4; ++j)
        acc[i][j] = __builtin_amdgcn_mfma_f32_16x16x32_bf16(a[i], b[j], acc[i][j], 0, 0, 0);
    __syncthreads();
  }

  #pragma unroll
  for (int j = 0; j < 4; ++j) {
    const int col = n0 + wc * 64 + j * 16 + lr;
    const float bv = bias[col];
    #pragma unroll
    for (int i = 0; i < 4; ++i) {
      #pragma unroll
      for (int r = 0; r < 4; ++r) {
        const int row = m0 + wr * 64 + i * 16 + lg * 4 + r;
        const float v = acc[i][j][r] + bv;
        if (OUT_F32) Cf[(size_t)row * N + col] = v;
        else         Cb[(size_t)row * N + col] = f2bf(v);
      }
    }
  }
}

// ----------------------------------------------------- causal flash attention
// R4 compute shape (4-wave blocks, 32 q-rows/wave, KVBLK=64) + uniform-duration
// complementary pairing (wave p does 32-row chunk p THEN chunk 63-p; 512 blocks
// = 2/CU, 8 waves/CU flat, no decay tail) + register double-buffered K-prefetch
// so QK^T never waits on memory (K latency hides under prev tile's softmax+PV).
// Swapped QK^T (lane owns one q-row slice), defer-max THR=8, Q pre-scaled 1/8.
__global__ __launch_bounds__(256, 2) void attn_fwd(
    const unsigned short* __restrict__ qkv,
    const unsigned short* __restrict__ Vt,
    unsigned short* __restrict__ out)
{
  __shared__ __align__(16) char Plds[4][32 * 128];   // per-wave [32 q][64 k] bf16, swizzled
  const int bid = blockIdx.x;
  const int bh = bid & 63;               // XCD = bh % 8, stable across g
  const int g  = bid >> 6;               // 0..7
  const int b = bh >> 4, h = bh & 15;
  const int w = threadIdx.x >> 6, l = threadIdx.x & 63;
  const int lr = l & 15, lg = l >> 4;
  const int pidx = g * 4 + w;            // 0..31

  const size_t rs = N3D;
  const unsigned short* Qb = qkv + (size_t)b * NS * rs + (size_t)h * NDH;
  const unsigned short* Kb = Qb + ND;
  const unsigned short* Vb = Vt + (size_t)bh * NDH * NS;

  char* pw = &Plds[w][0];
  const int swz = (lr & 7) << 4;

  #pragma unroll 1
  for (int pass = 0; pass < 2; ++pass) {
    const int q0 = (pass == 0 ? pidx : 63 - pidx) * 32;

    // Q fragments for rows q0+t*16+lr, pre-scaled by 1/8 (exact bf16 exp shift)
    short8 qf[2][2];
    #pragma unroll
    for (int t = 0; t < 2; ++t) {
      const unsigned short* qrow = Qb + (size_t)(q0 + t * 16 + lr) * rs + lg * 8;
      qf[t][0] = *(const short8*)(qrow);
      qf[t][1] = *(const short8*)(qrow + 32);
      #pragma unroll
      for (int j = 0; j < 8; ++j) {
        qf[t][0][j] = (short)f2bf(bf2f((unsigned short)qf[t][0][j]) * 0.125f);
        qf[t][1][j] = (short)f2bf(bf2f((unsigned short)qf[t][1][j]) * 0.125f);
      }
    }

    float m_run[2], l_run[2];
    f32x4 o[2][4] = {};
    m_run[0] = m_run[1] = -__builtin_inff();
    l_run[0] = l_run[1] = 0.f;

    const int ktmax = (q0 + 31) >> 6;

    // K prologue: tile 0 fragments into registers
    short8 kf[4][2];
    #pragma unroll
    for (int ks = 0; ks < 4; ++ks) {
      const unsigned short* krow = Kb + (size_t)(ks * 16 + lr) * rs + lg * 8;
      kf[ks][0] = *(const short8*)(krow);
      kf[ks][1] = *(const short8*)(krow + 32);
    }

    #pragma unroll 1
    for (int kt = 0; kt <= ktmax; ++kt) {
      const int kbase = kt << 6;

      // V fragments for this tile: lane holds V[kbase+kk*32+lg*8+j][nb*16+lr]
      short8 vf[4][2];
      #pragma unroll
      for (int nb = 0; nb < 4; ++nb)
        #pragma unroll
        for (int kk = 0; kk < 2; ++kk)
          vf[nb][kk] = *(const short8*)(Vb + (size_t)(nb * 16 + lr) * NS + kbase + kk * 32 + lg * 8);

      // K prefetch for next tile (latency hides under softmax+PV below)
      short8 kn[4][2];
      if (kt < ktmax) {
        #pragma unroll
        for (int ks = 0; ks < 4; ++ks) {
          const unsigned short* krow = Kb + (size_t)(kbase + 64 + ks * 16 + lr) * rs + lg * 8;
          kn[ks][0] = *(const short8*)(krow);
          kn[ks][1] = *(const short8*)(krow + 32);
        }
      }

      // swapped QK^T with already-resident kf: s[ks][t] = S^T[key][q=q0+t*16+lr]
      f32x4 s[4][2] = {};
      #pragma unroll
      for (int ks = 0; ks < 4; ++ks)
        #pragma unroll
        for (int t = 0; t < 2; ++t) {
          s[ks][t] = __builtin_amdgcn_mfma_f32_16x16x32_bf16(kf[ks][0], qf[t][0], s[ks][t], 0, 0, 0);
          s[ks][t] = __builtin_amdgcn_mfma_f32_16x16x32_bf16(kf[ks][1], qf[t][1], s[ks][t], 0, 0, 0);
        }

      const bool domask = (kbase + 63 > q0);   // wave-uniform
      #pragma unroll
      for (int t = 0; t < 2; ++t) {
        const int qi = q0 + t * 16 + lr;
        float v[16];
        #pragma unroll
        for (int ks = 0; ks < 4; ++ks)
          #pragma unroll
          for (int r = 0; r < 4; ++r)
            v[ks * 4 + r] = s[ks][t][r];
        if (domask) {
          #pragma unroll
          for (int ks = 0; ks < 4; ++ks)
            #pragma unroll
            for (int r = 0; r < 4; ++r)
              if (kbase + ks * 16 + lg * 4 + r > qi) v[ks * 4 + r] = -__builtin_inff();
        }
        // row max: local tree + 2 shuffles over the lg axis
        float a0 = fmaxf(v[0], v[1]),  a1 = fmaxf(v[2], v[3]);
        float a2 = fmaxf(v[4], v[5]),  a3 = fmaxf(v[6], v[7]);
        float a4 = fmaxf(v[8], v[9]),  a5 = fmaxf(v[10], v[11]);
        float a6 = fmaxf(v[12], v[13]), a7 = fmaxf(v[14], v[15]);
        float b0 = fmaxf(a0, a1), b1 = fmaxf(a2, a3), b2 = fmaxf(a4, a5), b3 = fmaxf(a6, a7);
        float mx = fmaxf(fmaxf(b0, b1), fmaxf(b2, b3));
        mx = fmaxf(mx, __shfl_xor(mx, 16));
        mx = fmaxf(mx, __shfl_xor(mx, 32));

        const float mold = m_run[t];
        if (__any(mx > mold + 8.0f)) {           // T13 defer-max
          const float mnew = fmaxf(mold, mx);
          const float sf = __expf(mold - mnew);
          m_run[t] = mnew;
          l_run[t] *= sf;
          #pragma unroll
          for (int rr = 0; rr < 4; ++rr) {
            const float sfo = __shfl(sf, lg * 4 + rr);
            #pragma unroll
            for (int nb = 0; nb < 4; ++nb) o[t][nb][rr] *= sfo;
          }
        }
        const float mc = m_run[t];
        float p[16];
        #pragma unroll
        for (int i = 0; i < 16; ++i) p[i] = __expf(v[i] - mc);
        float s0 = (p[0] + p[1]) + (p[2] + p[3]);
        float s1 = (p[4] + p[5]) + (p[6] + p[7]);
        float s2 = (p[8] + p[9]) + (p[10] + p[11]);
        float s3 = (p[12] + p[13]) + (p[14] + p[15]);
        float rsum = (s0 + s1) + (s2 + s3);
        rsum += __shfl_xor(rsum, 16);
        rsum += __shfl_xor(rsum, 32);
        l_run[t] += rsum;

        // P write: lane's 4 consecutive k at row q -> packed b64, swizzled
        #pragma unroll
        for (int ks = 0; ks < 4; ++ks) {
          us4 pk = {f2bf(p[ks * 4]), f2bf(p[ks * 4 + 1]), f2bf(p[ks * 4 + 2]), f2bf(p[ks * 4 + 3])};
          *(us4*)(pw + ((((t * 16 + lr) * 128) + ks * 32 + lg * 8) ^ swz)) = pk;
        }
      }

      asm volatile("s_waitcnt lgkmcnt(0)" ::: "memory");   // same-wave write->read
      __builtin_amdgcn_sched_barrier(0);

      #pragma unroll
      for (int t = 0; t < 2; ++t)
        #pragma unroll
        for (int kk = 0; kk < 2; ++kk) {
          short8 pf = *(const short8*)(pw + ((((t * 16 + lr) * 128) + kk * 64 + lg * 16) ^ swz));
          #pragma unroll
          for (int nb = 0; nb < 4; ++nb)
            o[t][nb] = __builtin_amdgcn_mfma_f32_16x16x32_bf16(pf, vf[nb][kk], o[t][nb], 0, 0, 0);
        }

      // rotate K double-buffer
      if (kt < ktmax) {
        #pragma unroll
        for (int ks = 0; ks < 4; ++ks) {
          kf[ks][0] = kn[ks][0];
          kf[ks][1] = kn[ks][1];
        }
      }
    }

    // epilogue: o rows are q=t*16+lg*4+rr; fetch row sum from owning lane
    #pragma unroll
    for (int t = 0; t < 2; ++t)
      #pragma unroll
      for (int rr = 0; rr < 4; ++rr) {
        const float lq = __shfl(l_run[t], lg * 4 + rr);
        const float inv = 1.0f / lq;
        const int qi = q0 + t * 16 + lg * 4 + rr;
        #pragma unroll
        for (int nb = 0; nb < 4; ++nb)
          out[(size_t)(b * NS + qi) * ND + h * NDH + nb * 16 + lr] = f2bf(o[t][nb][rr] * inv);
      }
  }
}

// --------------------------------------------------------------------- launch
extern "C" void kernel_launch(void* const* d_in, const int* in_sizes, int n_in,
                              void* d_out, int out_size, void* d_ws, size_t ws_size,
                              hipStream_t stream) {
  const float* x     = (const float*)d_in[0];
  const float* w_in  = (const float*)d_in[1];
  const float* b_in  = (const float*)d_in[2];
  const float* w_out = (const float*)d_in[3];
  const float* b_out = (const float*)d_in[4];
  float* out = (float*)d_out;

  char* ws = (char*)d_ws;
  size_t off = 0;
  unsigned short* x_bf    = (unsigned short*)(ws + off); off += (size_t)NM * ND * 2;    // 16 MiB
  unsigned short* qkv     = (unsigned short*)(ws + off); off += (size_t)NM * N3D * 2;   // 48 MiB
  unsigned short* attn    = (unsigned short*)(ws + off); off += (size_t)NM * ND * 2;    // 16 MiB
  unsigned short* w_in_t  = (unsigned short*)(ws + off); off += (size_t)N3D * ND * 2;   //  6 MiB
  unsigned short* w_out_t = (unsigned short*)(ws + off); off += (size_t)ND * ND * 2;    //  2 MiB
  // Vt aliases x_bf: x_bf is dead after GEMM1, vt_transpose runs after GEMM1.
  unsigned short* vt = x_bf;                                                            // 16 MiB

  // x -> bf16
  cvt_bf16_k<<<dim3((NM * ND) / (256 * 4)), 256, 0, stream>>>(x, x_bf, NM * ND);
  // weight transposes + cast: w[K][N] f32 -> wt[N][K] bf16
  transpose_cvt_k<<<dim3(N3D / 32, ND / 32), 256, 0, stream>>>(w_in, w_in_t, ND, N3D);
  transpose_cvt_k<<<dim3(ND / 32, ND / 32), 256, 0, stream>>>(w_out, w_out_t, ND, ND);

  // qkv = x @ w_in + b_in            (bf16 out)
  gemm_bt_bias<false><<<dim3((NM / 128) * (N3D / 128)), 256, 0, stream>>>(
      x_bf, w_in_t, b_in, qkv, nullptr, NM, N3D, ND);

  // V -> Vt (transposed per head)
  vt_transpose_k<<<dim3(64 * 64 * 2), 256, 0, stream>>>(qkv, vt);

  // attention: 512 uniform blocks (32-row complementary q-chunk pairing)
  attn_fwd<<<dim3(64 * 8), 256, 0, stream>>>(qkv, vt, attn);

  // out = attn @ w_out + b_out       (f32 out)
  gemm_bt_bias<true><<<dim3((NM / 128) * (ND / 128)), 256, 0, stream>>>(
      attn, w_out_t, b_out, nullptr, out, NM, ND, ND);
}

// Round 8
// 254.306 us; speedup vs baseline: 1.4351x; 1.0067x over previous
//
#include <hip/hip_runtime.h>
#include <hip/hip_bf16.h>
#include <cstdint>

#define NB 4
#define NS 2048
#define ND 1024
#define NH 16
#define NDH 64
#define NM (NB*NS)       // 8192
#define N3D (3*ND)       // 3072

typedef __attribute__((ext_vector_type(8))) short short8;
typedef __attribute__((ext_vector_type(4))) float f32x4;
typedef __attribute__((ext_vector_type(4))) unsigned short us4;
typedef __attribute__((ext_vector_type(2))) unsigned int uint2v;

__device__ __forceinline__ float bf2f(unsigned short u) {
  unsigned int i = ((unsigned int)u) << 16;
  return __builtin_bit_cast(float, i);
}
__device__ __forceinline__ unsigned short f2bf(float f) {
  unsigned int i = __builtin_bit_cast(unsigned int, f);
  i = (i + 0x7FFFu + ((i >> 16) & 1u)) >> 16;
  return (unsigned short)i;
}
// packed 2x bf16 (RNE) from two f32 — T12 recipe, no builtin on gfx950
__device__ __forceinline__ unsigned int cvtpk_bf16(float lo, float hi) {
  unsigned int r;
  asm("v_cvt_pk_bf16_f32 %0, %1, %2" : "=v"(r) : "v"(lo), "v"(hi));
  return r;
}

#define GLD16(g, l) __builtin_amdgcn_global_load_lds( \
    (__attribute__((address_space(1))) void*)(void*)(g), \
    (__attribute__((address_space(3))) void*)(l), 16, 0, 0)

// ------------------------------------------------------------ f32 -> bf16 cast
__global__ __launch_bounds__(256) void cvt_bf16_k(
    const float* __restrict__ in, unsigned short* __restrict__ out, int n)
{
  const int i = (blockIdx.x * 256 + threadIdx.x) * 4;
  if (i + 3 < n) {
    const f32x4 v = *(const f32x4*)(in + i);
    us4 o = {f2bf(v[0]), f2bf(v[1]), f2bf(v[2]), f2bf(v[3])};
    *(us4*)(out + i) = o;
  }
}

// --------------------------------------------- f32 [rows][cols] -> bf16 [cols][rows]
__global__ __launch_bounds__(256) void transpose_cvt_k(
    const float* __restrict__ in, unsigned short* __restrict__ out,
    int rows, int cols)
{
  __shared__ unsigned short tile[32][33];
  const int c0 = blockIdx.x * 32, r0 = blockIdx.y * 32;
  const int tx = threadIdx.x & 31, ty = threadIdx.x >> 5;   // ty 0..7
  #pragma unroll
  for (int i = ty; i < 32; i += 8)
    tile[i][tx] = f2bf(in[(size_t)(r0 + i) * cols + (c0 + tx)]);
  __syncthreads();
  #pragma unroll
  for (int i = ty; i < 32; i += 8)
    out[(size_t)(c0 + i) * rows + (r0 + tx)] = tile[tx][i];
}

// ---------------------------------- V columns of qkv -> Vt[bh][d=64][s=2048]
__global__ __launch_bounds__(256) void vt_transpose_k(
    const unsigned short* __restrict__ qkv, unsigned short* __restrict__ vt)
{
  __shared__ unsigned short tile[32][33];
  const int dt = blockIdx.x & 1;           // 2 d-tiles
  const int st = (blockIdx.x >> 1) & 63;   // 64 s-tiles
  const int bh = blockIdx.x >> 7;          // 64 (b,h)
  const int b = bh >> 4, h = bh & 15;
  const int tx = threadIdx.x & 31, ty = threadIdx.x >> 5;
  const int s0 = st * 32, d0 = dt * 32;
  const unsigned short* src = qkv + (size_t)b * NS * N3D + 2 * ND + h * NDH;
  #pragma unroll
  for (int i = ty; i < 32; i += 8)
    tile[i][tx] = src[(size_t)(s0 + i) * N3D + d0 + tx];
  __syncthreads();
  unsigned short* dst = vt + (size_t)bh * NDH * NS;
  #pragma unroll
  for (int i = ty; i < 32; i += 8)
    dst[(size_t)(d0 + i) * NS + s0 + tx] = tile[tx][i];
}

// ------------------------------------------------- GEMM  C = A * Bt^T + bias
// A[M][K] bf16 row-major, Bt[N][K] bf16 row-major, f32 bias. 128x128 tile,
// BK=32, 4 waves (2x2 of 64x64), global_load_lds staging (m97 structure).
// XCD-aware bijective blockIdx swizzle (T1; nwg % 8 == 0 for all our shapes).
template<bool OUT_F32>
__global__ __launch_bounds__(256) void gemm_bt_bias(
    const unsigned short* __restrict__ A,
    const unsigned short* __restrict__ Bt,
    const float* __restrict__ bias,
    unsigned short* __restrict__ Cb,
    float* __restrict__ Cf,
    int M, int N, int K)
{
  __shared__ __align__(16) unsigned short Alds[128 * 32];
  __shared__ __align__(16) unsigned short Blds[128 * 32];
  const int nbn = N >> 7;
  const int nwg = (M >> 7) * nbn;
  const int cpx = nwg >> 3;
  const int tid = (blockIdx.x & 7) * cpx + (blockIdx.x >> 3);
  const int bm = tid / nbn, bn = tid % nbn;
  const int m0 = bm << 7, n0 = bn << 7;
  const int w = threadIdx.x >> 6, l = threadIdx.x & 63;
  const int wr = w >> 1, wc = w & 1;
  const int lr = l & 15, lg = l >> 4;

  const unsigned short* gA = A + (size_t)(m0 + w * 32 + (l >> 2)) * K + (l & 3) * 8;
  const unsigned short* gB = Bt + (size_t)(n0 + w * 32 + (l >> 2)) * K + (l & 3) * 8;
  unsigned short* lA = Alds + (w * 32) * 32;   // wave-uniform LDS base
  unsigned short* lB = Blds + (w * 32) * 32;

  f32x4 acc[4][4] = {};

  for (int k0 = 0; k0 < K; k0 += 32) {
    GLD16(gA + k0, lA);
    GLD16(gA + k0 + (size_t)16 * K, lA + 16 * 32);
    GLD16(gB + k0, lB);
    GLD16(gB + k0 + (size_t)16 * K, lB + 16 * 32);
    __syncthreads();

    short8 a[4], b[4];
    #pragma unroll
    for (int i = 0; i < 4; ++i)
      a[i] = *(const short8*)(Alds + (wr * 64 + i * 16 + lr) * 32 + lg * 8);
    #pragma unroll
    for (int j = 0; j < 4; ++j)
      b[j] = *(const short8*)(Blds + (wc * 64 + j * 16 + lr) * 32 + lg * 8);

    #pragma unroll
    for (int i = 0; i < 4; ++i)
      #pragma unroll
      for (int j = 0; j < 4; ++j)
        acc[i][j] = __builtin_amdgcn_mfma_f32_16x16x32_bf16(a[i], b[j], acc[i][j], 0, 0, 0);
    __syncthreads();
  }

  #pragma unroll
  for (int j = 0; j < 4; ++j) {
    const int col = n0 + wc * 64 + j * 16 + lr;
    const float bv = bias[col];
    #pragma unroll
    for (int i = 0; i < 4; ++i) {
      #pragma unroll
      for (int r = 0; r < 4; ++r) {
        const int row = m0 + wr * 64 + i * 16 + lg * 4 + r;
        const float v = acc[i][j][r] + bv;
        if (OUT_F32) Cf[(size_t)row * N + col] = v;
        else         Cb[(size_t)row * N + col] = f2bf(v);
      }
    }
  }
}

// ----------------------------------------------------- causal flash attention
// R7 structure (4-wave blocks, 32 q-rows/wave, KVBLK=64, complementary pairing,
// register double-buffered K-prefetch) + shuffle-free steady-state softmax:
// defer-max trigger on LOCAL max (SALU __any), exact row-max reduce only in the
// rare rescale branch; l_run kept as per-lane partial, reduced once per chunk.
// P pack via v_cvt_pk_bf16_f32 (T12). Serial DS chain/iter: ~1200cy -> ~240cy.
__global__ __launch_bounds__(256, 2) void attn_fwd(
    const unsigned short* __restrict__ qkv,
    const unsigned short* __restrict__ Vt,
    unsigned short* __restrict__ out)
{
  __shared__ __align__(16) char Plds[4][32 * 128];   // per-wave [32 q][64 k] bf16, swizzled
  const int bid = blockIdx.x;
  const int bh = bid & 63;               // XCD = bh % 8, stable across g
  const int g  = bid >> 6;               // 0..7
  const int b = bh >> 4, h = bh & 15;
  const int w = threadIdx.x >> 6, l = threadIdx.x & 63;
  const int lr = l & 15, lg = l >> 4;
  const int pidx = g * 4 + w;            // 0..31

  const size_t rs = N3D;
  const unsigned short* Qb = qkv + (size_t)b * NS * rs + (size_t)h * NDH;
  const unsigned short* Kb = Qb + ND;
  const unsigned short* Vb = Vt + (size_t)bh * NDH * NS;

  char* pw = &Plds[w][0];
  const int swz = (lr & 7) << 4;

  #pragma unroll 1
  for (int pass = 0; pass < 2; ++pass) {
    const int q0 = (pass == 0 ? pidx : 63 - pidx) * 32;

    // Q fragments for rows q0+t*16+lr, pre-scaled by 1/8 (exact bf16 exp shift)
    short8 qf[2][2];
    #pragma unroll
    for (int t = 0; t < 2; ++t) {
      const unsigned short* qrow = Qb + (size_t)(q0 + t * 16 + lr) * rs + lg * 8;
      qf[t][0] = *(const short8*)(qrow);
      qf[t][1] = *(const short8*)(qrow + 32);
      #pragma unroll
      for (int j = 0; j < 8; ++j) {
        qf[t][0][j] = (short)f2bf(bf2f((unsigned short)qf[t][0][j]) * 0.125f);
        qf[t][1][j] = (short)f2bf(bf2f((unsigned short)qf[t][1][j]) * 0.125f);
      }
    }

    float m_run[2], l_run[2];          // l_run is a per-lane PARTIAL row sum
    f32x4 o[2][4] = {};
    m_run[0] = m_run[1] = -__builtin_inff();
    l_run[0] = l_run[1] = 0.f;

    const int ktmax = (q0 + 31) >> 6;

    // K prologue: tile 0 fragments into registers
    short8 kf[4][2];
    #pragma unroll
    for (int ks = 0; ks < 4; ++ks) {
      const unsigned short* krow = Kb + (size_t)(ks * 16 + lr) * rs + lg * 8;
      kf[ks][0] = *(const short8*)(krow);
      kf[ks][1] = *(const short8*)(krow + 32);
    }

    #pragma unroll 1
    for (int kt = 0; kt <= ktmax; ++kt) {
      const int kbase = kt << 6;

      // V fragments for this tile: lane holds V[kbase+kk*32+lg*8+j][nb*16+lr]
      short8 vf[4][2];
      #pragma unroll
      for (int nb = 0; nb < 4; ++nb)
        #pragma unroll
        for (int kk = 0; kk < 2; ++kk)
          vf[nb][kk] = *(const short8*)(Vb + (size_t)(nb * 16 + lr) * NS + kbase + kk * 32 + lg * 8);

      // K prefetch for next tile (latency hides under softmax+PV below)
      short8 kn[4][2];
      if (kt < ktmax) {
        #pragma unroll
        for (int ks = 0; ks < 4; ++ks) {
          const unsigned short* krow = Kb + (size_t)(kbase + 64 + ks * 16 + lr) * rs + lg * 8;
          kn[ks][0] = *(const short8*)(krow);
          kn[ks][1] = *(const short8*)(krow + 32);
        }
      }

      // swapped QK^T with already-resident kf: s[ks][t] = S^T[key][q=q0+t*16+lr]
      f32x4 s[4][2] = {};
      #pragma unroll
      for (int ks = 0; ks < 4; ++ks)
        #pragma unroll
        for (int t = 0; t < 2; ++t) {
          s[ks][t] = __builtin_amdgcn_mfma_f32_16x16x32_bf16(kf[ks][0], qf[t][0], s[ks][t], 0, 0, 0);
          s[ks][t] = __builtin_amdgcn_mfma_f32_16x16x32_bf16(kf[ks][1], qf[t][1], s[ks][t], 0, 0, 0);
        }

      const bool domask = (kbase + 63 > q0);   // wave-uniform
      #pragma unroll
      for (int t = 0; t < 2; ++t) {
        const int qi = q0 + t * 16 + lr;
        float v[16];
        #pragma unroll
        for (int ks = 0; ks < 4; ++ks)
          #pragma unroll
          for (int r = 0; r < 4; ++r)
            v[ks * 4 + r] = s[ks][t][r];
        if (domask) {
          #pragma unroll
          for (int ks = 0; ks < 4; ++ks)
            #pragma unroll
            for (int r = 0; r < 4; ++r)
              if (kbase + ks * 16 + lg * 4 + r > qi) v[ks * 4 + r] = -__builtin_inff();
        }
        // LOCAL max only (15 fmax, no cross-lane in the common path)
        float a0 = fmaxf(v[0], v[1]),  a1 = fmaxf(v[2], v[3]);
        float a2 = fmaxf(v[4], v[5]),  a3 = fmaxf(v[6], v[7]);
        float a4 = fmaxf(v[8], v[9]),  a5 = fmaxf(v[10], v[11]);
        float a6 = fmaxf(v[12], v[13]), a7 = fmaxf(v[14], v[15]);
        float b0 = fmaxf(a0, a1), b1 = fmaxf(a2, a3), b2 = fmaxf(a4, a5), b3 = fmaxf(a6, a7);
        float mx = fmaxf(fmaxf(b0, b1), fmaxf(b2, b3));

        const float mold = m_run[t];
        if (__any(mx > mold + 8.0f)) {       // rare: exact reduce + rescale
          float rmx = fmaxf(mx, __shfl_xor(mx, 16));
          rmx = fmaxf(rmx, __shfl_xor(rmx, 32));
          const float mnew = fmaxf(mold, rmx);
          const float sf = __expf(mold - mnew);
          m_run[t] = mnew;
          l_run[t] *= sf;
          #pragma unroll
          for (int rr = 0; rr < 4; ++rr) {
            const float sfo = __shfl(sf, lg * 4 + rr);
            #pragma unroll
            for (int nb = 0; nb < 4; ++nb) o[t][nb][rr] *= sfo;
          }
        }
        const float mc = m_run[t];
        float p[16];
        #pragma unroll
        for (int i = 0; i < 16; ++i) p[i] = __expf(v[i] - mc);
        // per-lane PARTIAL row sum (no shuffles; reduced once in epilogue)
        float s0 = (p[0] + p[1]) + (p[2] + p[3]);
        float s1 = (p[4] + p[5]) + (p[6] + p[7]);
        float s2 = (p[8] + p[9]) + (p[10] + p[11]);
        float s3 = (p[12] + p[13]) + (p[14] + p[15]);
        l_run[t] += (s0 + s1) + (s2 + s3);

        // P pack via v_cvt_pk_bf16_f32 + swizzled b64 writes
        #pragma unroll
        for (int ks = 0; ks < 4; ++ks) {
          uint2v pk = {cvtpk_bf16(p[ks * 4],     p[ks * 4 + 1]),
                       cvtpk_bf16(p[ks * 4 + 2], p[ks * 4 + 3])};
          *(uint2v*)(pw + ((((t * 16 + lr) * 128) + ks * 32 + lg * 8) ^ swz)) = pk;
        }
      }

      asm volatile("s_waitcnt lgkmcnt(0)" ::: "memory");   // same-wave write->read
      __builtin_amdgcn_sched_barrier(0);

      #pragma unroll
      for (int t = 0; t < 2; ++t)
        #pragma unroll
        for (int kk = 0; kk < 2; ++kk) {
          short8 pf = *(const short8*)(pw + ((((t * 16 + lr) * 128) + kk * 64 + lg * 16) ^ swz));
          #pragma unroll
          for (int nb = 0; nb < 4; ++nb)
            o[t][nb] = __builtin_amdgcn_mfma_f32_16x16x32_bf16(pf, vf[nb][kk], o[t][nb], 0, 0, 0);
        }

      // rotate K double-buffer
      if (kt < ktmax) {
        #pragma unroll
        for (int ks = 0; ks < 4; ++ks) {
          kf[ks][0] = kn[ks][0];
          kf[ks][1] = kn[ks][1];
        }
      }
    }

    // epilogue: reduce the per-lane l_run partials (once per chunk), normalize
    #pragma unroll
    for (int t = 0; t < 2; ++t) {
      float lt = l_run[t];
      lt += __shfl_xor(lt, 16);
      lt += __shfl_xor(lt, 32);
      #pragma unroll
      for (int rr = 0; rr < 4; ++rr) {
        const float lq = __shfl(lt, lg * 4 + rr);
        const float inv = 1.0f / lq;
        const int qi = q0 + t * 16 + lg * 4 + rr;
        #pragma unroll
        for (int nb = 0; nb < 4; ++nb)
          out[(size_t)(b * NS + qi) * ND + h * NDH + nb * 16 + lr] = f2bf(o[t][nb][rr] * inv);
      }
    }
  }
}

// --------------------------------------------------------------------- launch
extern "C" void kernel_launch(void* const* d_in, const int* in_sizes, int n_in,
                              void* d_out, int out_size, void* d_ws, size_t ws_size,
                              hipStream_t stream) {
  const float* x     = (const float*)d_in[0];
  const float* w_in  = (const float*)d_in[1];
  const float* b_in  = (const float*)d_in[2];
  const float* w_out = (const float*)d_in[3];
  const float* b_out = (const float*)d_in[4];
  float* out = (float*)d_out;

  char* ws = (char*)d_ws;
  size_t off = 0;
  unsigned short* x_bf    = (unsigned short*)(ws + off); off += (size_t)NM * ND * 2;    // 16 MiB
  unsigned short* qkv     = (unsigned short*)(ws + off); off += (size_t)NM * N3D * 2;   // 48 MiB
  unsigned short* attn    = (unsigned short*)(ws + off); off += (size_t)NM * ND * 2;    // 16 MiB
  unsigned short* w_in_t  = (unsigned short*)(ws + off); off += (size_t)N3D * ND * 2;   //  6 MiB
  unsigned short* w_out_t = (unsigned short*)(ws + off); off += (size_t)ND * ND * 2;    //  2 MiB
  // Vt aliases x_bf: x_bf is dead after GEMM1, vt_transpose runs after GEMM1.
  unsigned short* vt = x_bf;                                                            // 16 MiB

  // x -> bf16
  cvt_bf16_k<<<dim3((NM * ND) / (256 * 4)), 256, 0, stream>>>(x, x_bf, NM * ND);
  // weight transposes + cast: w[K][N] f32 -> wt[N][K] bf16
  transpose_cvt_k<<<dim3(N3D / 32, ND / 32), 256, 0, stream>>>(w_in, w_in_t, ND, N3D);
  transpose_cvt_k<<<dim3(ND / 32, ND / 32), 256, 0, stream>>>(w_out, w_out_t, ND, ND);

  // qkv = x @ w_in + b_in            (bf16 out)
  gemm_bt_bias<false><<<dim3((NM / 128) * (N3D / 128)), 256, 0, stream>>>(
      x_bf, w_in_t, b_in, qkv, nullptr, NM, N3D, ND);

  // V -> Vt (transposed per head)
  vt_transpose_k<<<dim3(64 * 64 * 2), 256, 0, stream>>>(qkv, vt);

  // attention: 512 uniform blocks (32-row complementary q-chunk pairing)
  attn_fwd<<<dim3(64 * 8), 256, 0, stream>>>(qkv, vt, attn);

  // out = attn @ w_out + b_out       (f32 out)
  gemm_bt_bias<true><<<dim3((NM / 128) * (ND / 128)), 256, 0, stream>>>(
      attn, w_out_t, b_out, nullptr, out, NM, ND, ND);
}